// Round 2
// baseline (11525.880 us; speedup 1.0000x reference)
//
#include <hip/hip_runtime.h>
#include <hip/hip_bf16.h>
#include <math.h>

#define NNODES 50000
#define NEDGES 200000

using bf16 = __hip_bfloat16;

// ---------- typed load/store helpers ----------
static __device__ __forceinline__ float ldf(const float* p) { return *p; }
static __device__ __forceinline__ float ldf(const bf16* p)  { return __bfloat162float(*p); }
static __device__ __forceinline__ void  stf(float* p, float v) { *p = v; }
static __device__ __forceinline__ void  stf(bf16* p,  float v) { *p = __float2bfloat16(v); }

// monotone float<->uint encode for atomicMax-based float max
static __device__ __forceinline__ unsigned enc_f(float f) {
    unsigned u = __float_as_uint(f);
    return (u & 0x80000000u) ? ~u : (u | 0x80000000u);
}
static __device__ __forceinline__ float dec_f(unsigned u) {
    u = (u & 0x80000000u) ? (u & 0x7FFFFFFFu) : ~u;
    return __uint_as_float(u);
}

// ---------- GEMM: C[N,Mo] = A[N,K]*W[K,Mo] + bias ----------
template<typename TO>
__global__ __launch_bounds__(256) void gemm_bias(
    const float* __restrict__ A, const float* __restrict__ W,
    const float* __restrict__ bias, TO* __restrict__ C,
    int N, int K, int Mo) {
  __shared__ float As[16][65];
  __shared__ float Ws[16][65];
  const int tid = threadIdx.x;
  const int tx = tid & 15, ty = tid >> 4;
  const int brow = blockIdx.x * 64, bcol = blockIdx.y * 64;
  float acc[4][4] = {};
  const int lr = tid >> 2;        // A-tile row 0..63
  const int lc = (tid & 3) * 4;   // A-tile k 0,4,8,12
  const int wr = tid >> 4;        // W-tile k 0..15
  const int wc = (tid & 15) * 4;  // W-tile col
  for (int k0 = 0; k0 < K; k0 += 16) {
    {
      int row = brow + lr;
      float4 v = make_float4(0.f, 0.f, 0.f, 0.f);
      if (row < N) v = *reinterpret_cast<const float4*>(&A[(size_t)row * K + k0 + lc]);
      As[lc + 0][lr] = v.x; As[lc + 1][lr] = v.y;
      As[lc + 2][lr] = v.z; As[lc + 3][lr] = v.w;
    }
    {
      float4 v = *reinterpret_cast<const float4*>(&W[(size_t)(k0 + wr) * Mo + bcol + wc]);
      Ws[wr][wc + 0] = v.x; Ws[wr][wc + 1] = v.y;
      Ws[wr][wc + 2] = v.z; Ws[wr][wc + 3] = v.w;
    }
    __syncthreads();
    #pragma unroll
    for (int k = 0; k < 16; ++k) {
      float a[4], b[4];
      #pragma unroll
      for (int i = 0; i < 4; ++i) a[i] = As[k][ty * 4 + i];
      #pragma unroll
      for (int j = 0; j < 4; ++j) b[j] = Ws[k][tx * 4 + j];
      #pragma unroll
      for (int i = 0; i < 4; ++i)
        #pragma unroll
        for (int j = 0; j < 4; ++j) acc[i][j] += a[i] * b[j];
    }
    __syncthreads();
  }
  #pragma unroll
  for (int i = 0; i < 4; ++i) {
    int row = brow + ty * 4 + i;
    if (row >= N) continue;
    #pragma unroll
    for (int j = 0; j < 4; ++j)
      stf(&C[(size_t)row * Mo + bcol + tx * 4 + j],
          acc[i][j] + bias[bcol + tx * 4 + j]);
  }
}

// ---------- per-layer prep: zero acc, init segmax/segsum ----------
__global__ void prep_kernel(float* __restrict__ acc, unsigned* __restrict__ mmax,
                            float* __restrict__ ssum, int nacc, int nseg) {
  int t = blockIdx.x * blockDim.x + threadIdx.x;
  if (t < nacc) acc[t] = 0.f;
  if (t < nseg) { mmax[t] = 0x007FFFFFu; ssum[t] = 0.f; }  // enc(-inf)
}

// ---------- edge attention logits + segment max ----------
template<int H, int C, typename TL, typename TR>
__global__ __launch_bounds__(256) void edge_att(
    const int* __restrict__ ei, const TL* __restrict__ xl,
    const TR* __restrict__ xr, const float* __restrict__ att,
    float* __restrict__ ebuf, unsigned* __restrict__ mmax) {
  constexpr int HC = H * C;
  constexpr int CPL = HC / 64;      // channels per lane
  constexpr int GROUP = C / CPL;    // lanes per head
  const int wave = (blockIdx.x * blockDim.x + threadIdx.x) >> 6;
  const int lane = threadIdx.x & 63;
  if (wave >= NEDGES) return;
  const int src = ei[wave];
  const int dst = ei[NEDGES + wave];
  const TL* pl = xl + (size_t)src * HC + lane * CPL;
  const TR* pr = xr + (size_t)dst * HC + lane * CPL;
  const float* pa = att + lane * CPL;
  float sum = 0.f;
  #pragma unroll
  for (int c = 0; c < CPL; ++c) {
    float z = ldf(&pl[c]) + ldf(&pr[c]);
    z = (z > 0.f) ? z : 0.2f * z;
    sum += z * pa[c];
  }
  #pragma unroll
  for (int off = 1; off < GROUP; off <<= 1)
    sum += __shfl_xor(sum, off, 64);
  if ((lane & (GROUP - 1)) == 0) {
    int h = lane / GROUP;
    ebuf[(size_t)wave * H + h] = sum;
    atomicMax(&mmax[(size_t)dst * H + h], enc_f(sum));
  }
}

// ---------- exp(e - max) and segment sum ----------
template<int H>
__global__ void edge_expsum(const int* __restrict__ ei, float* __restrict__ ebuf,
                            const unsigned* __restrict__ mmax, float* __restrict__ ssum) {
  int t = blockIdx.x * blockDim.x + threadIdx.x;
  if (t >= NEDGES * H) return;
  int e = t / H, h = t - e * H;
  int dst = ei[NEDGES + e];
  float m = dec_f(mmax[dst * H + h]);
  float ex = __expf(ebuf[t] - m);
  ebuf[t] = ex;
  atomicAdd(&ssum[dst * H + h], ex);
}

// ---------- scatter: acc[dst] += alpha * xl[src] ----------
template<int H, int C, typename TL>
__global__ __launch_bounds__(256) void edge_scatter(
    const int* __restrict__ ei, const TL* __restrict__ xl,
    const float* __restrict__ ebuf, const float* __restrict__ ssum,
    float* __restrict__ acc) {
  constexpr int HC = H * C;
  constexpr int CPL = HC / 64;
  constexpr int GROUP = C / CPL;
  const int wave = (blockIdx.x * blockDim.x + threadIdx.x) >> 6;
  const int lane = threadIdx.x & 63;
  if (wave >= NEDGES) return;
  const int src = ei[wave];
  const int dst = ei[NEDGES + wave];
  const int h = lane / GROUP;
  const float alpha = ebuf[(size_t)wave * H + h] /
                      (ssum[(size_t)dst * H + h] + 1e-16f);
  const TL* pl = xl + (size_t)src * HC + lane * CPL;
  float* pa = acc + (size_t)dst * HC + lane * CPL;
  #pragma unroll
  for (int c = 0; c < CPL; ++c)
    atomicAdd(&pa[c], alpha * ldf(&pl[c]));
}

// ---------- epilogues ----------
__global__ void elu_bias(float* __restrict__ acc, const float* __restrict__ b, int total) {
  int t = blockIdx.x * blockDim.x + threadIdx.x;
  if (t >= total) return;
  float v = acc[t] + b[t & 511];
  acc[t] = v > 0.f ? v : (__expf(v) - 1.f);
}

__global__ void final_bias(const float* __restrict__ acc, const float* __restrict__ b,
                           float* __restrict__ out) {
  int t = blockIdx.x * blockDim.x + threadIdx.x;
  if (t >= NNODES * 64) return;
  out[t] = acc[t] + b[t & 63];
}

// ---------- emergency: report ws_size via absmax ----------
__global__ void report_ws(float* __restrict__ out, float v) { out[0] = v; }

// ---------- pipeline ----------
template<typename TL, typename TR>
static void run_pipeline(const float* x, const int* ei, void* const* d_in,
                         float* out, char* ws, hipStream_t stream) {
  float* acc = (float*)ws;
  size_t off = 102400000;                       // N*512*4
  TL* xlb = (TL*)(ws + off); off += (size_t)NNODES * 512 * sizeof(TL);
  TR* xrb = (TR*)(ws + off); off += (size_t)NNODES * 512 * sizeof(TR);
  float*    ebuf = (float*)(ws + off);
  unsigned* mmax = (unsigned*)(ws + off + 3200000);
  float*    ssum = (float*)(ws + off + 4000000);

  const int egrid = (NEDGES * 64 + 255) / 256;  // one wave per edge

  for (int layer = 0; layer < 4; ++layer) {
    const int base = 2 + layer * 6;
    const float* Wl  = (const float*)d_in[base + 0];
    const float* bl  = (const float*)d_in[base + 1];
    const float* Wr  = (const float*)d_in[base + 2];
    const float* br  = (const float*)d_in[base + 3];
    const float* att = (const float*)d_in[base + 4];
    const float* b   = (const float*)d_in[base + 5];

    const float* h_in = (layer == 0) ? x : acc;
    const int K  = (layer == 0) ? 128 : 512;
    const int H  = (layer == 3) ? 1 : 4;
    const int HC = (layer == 3) ? 64 : 512;

    dim3 ggrid((NNODES + 63) / 64, HC / 64);
    gemm_bias<TL><<<ggrid, 256, 0, stream>>>(h_in, Wl, bl, xlb, NNODES, K, HC);
    gemm_bias<TR><<<ggrid, 256, 0, stream>>>(h_in, Wr, br, xrb, NNODES, K, HC);

    int nacc = NNODES * HC, nseg = NNODES * H;
    prep_kernel<<<(nacc + 255) / 256, 256, 0, stream>>>(acc, mmax, ssum, nacc, nseg);

    if (layer < 3) {
      edge_att<4, 128, TL, TR><<<egrid, 256, 0, stream>>>(ei, xlb, xrb, att, ebuf, mmax);
      edge_expsum<4><<<(NEDGES * 4 + 255) / 256, 256, 0, stream>>>(ei, ebuf, mmax, ssum);
      edge_scatter<4, 128, TL><<<egrid, 256, 0, stream>>>(ei, xlb, ebuf, ssum, acc);
      elu_bias<<<(nacc + 255) / 256, 256, 0, stream>>>(acc, b, nacc);
    } else {
      edge_att<1, 64, TL, TR><<<egrid, 256, 0, stream>>>(ei, xlb, xrb, att, ebuf, mmax);
      edge_expsum<1><<<(NEDGES + 255) / 256, 256, 0, stream>>>(ei, ebuf, mmax, ssum);
      edge_scatter<1, 64, TL><<<egrid, 256, 0, stream>>>(ei, xlb, ebuf, ssum, acc);
      final_bias<<<(NNODES * 64 + 255) / 256, 256, 0, stream>>>(acc, b, out);
    }
  }
}

// ---------- orchestration ----------
extern "C" void kernel_launch(void* const* d_in, const int* in_sizes, int n_in,
                              void* d_out, int out_size, void* d_ws, size_t ws_size,
                              hipStream_t stream) {
  const float* x  = (const float*)d_in[0];
  const int*   ei = (const int*)d_in[1];
  float* out = (float*)d_out;
  char* ws = (char*)d_ws;

  const size_t accB = 102400000ull;   // N*512*4
  const size_t f32B = 102400000ull;   // per fp32 xl/xr buffer
  const size_t b16B = 51200000ull;    // per bf16 xl/xr buffer
  const size_t tailB = 4800000ull;    // ebuf + mmax + ssum

  if (ws_size >= accB + 2 * f32B + tailB) {
    run_pipeline<float, float>(x, ei, d_in, out, ws, stream);
  } else if (ws_size >= accB + f32B + b16B + tailB) {
    run_pipeline<float, bf16>(x, ei, d_in, out, ws, stream);
  } else if (ws_size >= accB + 2 * b16B + tailB) {
    run_pipeline<bf16, bf16>(x, ei, d_in, out, ws, stream);
  } else {
    // not enough workspace for any layout: encode ws_size into the output
    // so the reported absmax reveals the actual size.
    report_ws<<<1, 1, 0, stream>>>(out, (float)ws_size);
  }
}

// Round 3
// 3158.474 us; speedup vs baseline: 3.6492x; 3.6492x over previous
//
#include <hip/hip_runtime.h>
#include <hip/hip_bf16.h>
#include <math.h>

#define NNODES 50000
#define NEDGES 200000

using bf16 = __hip_bfloat16;

// ---------- typed load/store helpers ----------
static __device__ __forceinline__ float ldf(const float* p) { return *p; }
static __device__ __forceinline__ float ldf(const bf16* p)  { return __bfloat162float(*p); }
static __device__ __forceinline__ void  stf(float* p, float v) { *p = v; }
static __device__ __forceinline__ void  stf(bf16* p,  float v) { *p = __float2bfloat16(v); }

// ---------- GEMM: C[N,Mo] = A[N,K]*W[K,Mo] + bias ----------
template<typename TO>
__global__ __launch_bounds__(256) void gemm_bias(
    const float* __restrict__ A, const float* __restrict__ W,
    const float* __restrict__ bias, TO* __restrict__ C,
    int N, int K, int Mo) {
  __shared__ float As[16][65];
  __shared__ float Ws[16][65];
  const int tid = threadIdx.x;
  const int tx = tid & 15, ty = tid >> 4;
  const int brow = blockIdx.x * 64, bcol = blockIdx.y * 64;
  float acc[4][4] = {};
  const int lr = tid >> 2;        // A-tile row 0..63
  const int lc = (tid & 3) * 4;   // A-tile k 0,4,8,12
  const int wr = tid >> 4;        // W-tile k 0..15
  const int wc = (tid & 15) * 4;  // W-tile col
  for (int k0 = 0; k0 < K; k0 += 16) {
    {
      int row = brow + lr;
      float4 v = make_float4(0.f, 0.f, 0.f, 0.f);
      if (row < N) v = *reinterpret_cast<const float4*>(&A[(size_t)row * K + k0 + lc]);
      As[lc + 0][lr] = v.x; As[lc + 1][lr] = v.y;
      As[lc + 2][lr] = v.z; As[lc + 3][lr] = v.w;
    }
    {
      float4 v = *reinterpret_cast<const float4*>(&W[(size_t)(k0 + wr) * Mo + bcol + wc]);
      Ws[wr][wc + 0] = v.x; Ws[wr][wc + 1] = v.y;
      Ws[wr][wc + 2] = v.z; Ws[wr][wc + 3] = v.w;
    }
    __syncthreads();
    #pragma unroll
    for (int k = 0; k < 16; ++k) {
      float a[4], b[4];
      #pragma unroll
      for (int i = 0; i < 4; ++i) a[i] = As[k][ty * 4 + i];
      #pragma unroll
      for (int j = 0; j < 4; ++j) b[j] = Ws[k][tx * 4 + j];
      #pragma unroll
      for (int i = 0; i < 4; ++i)
        #pragma unroll
        for (int j = 0; j < 4; ++j) acc[i][j] += a[i] * b[j];
    }
    __syncthreads();
  }
  #pragma unroll
  for (int i = 0; i < 4; ++i) {
    int row = brow + ty * 4 + i;
    if (row >= N) continue;
    #pragma unroll
    for (int j = 0; j < 4; ++j)
      stf(&C[(size_t)row * Mo + bcol + tx * 4 + j],
          acc[i][j] + bias[bcol + tx * 4 + j]);
  }
}

// ---------- CSR build (by dst) ----------
__global__ void csr_zero(int* __restrict__ deg) {
  int t = blockIdx.x * blockDim.x + threadIdx.x;
  if (t < NNODES) deg[t] = 0;
}
__global__ void csr_hist(const int* __restrict__ ei, int* __restrict__ deg) {
  int e = blockIdx.x * blockDim.x + threadIdx.x;
  if (e >= NEDGES) return;
  atomicAdd(&deg[ei[NEDGES + e]], 1);
}
__global__ __launch_bounds__(1024) void csr_scan(const int* __restrict__ deg,
                                                 int* __restrict__ off,
                                                 int* __restrict__ pos) {
  __shared__ int sums[1024];
  const int tid = threadIdx.x;
  const int chunk = (NNODES + 1023) / 1024;
  const int start = tid * chunk;
  const int end = (start + chunk < NNODES) ? (start + chunk) : NNODES;
  int local = 0;
  for (int i = start; i < end; ++i) local += deg[i];
  sums[tid] = local;
  __syncthreads();
  for (int d = 1; d < 1024; d <<= 1) {
    int v = (tid >= d) ? sums[tid - d] : 0;
    __syncthreads();
    sums[tid] += v;
    __syncthreads();
  }
  int run = (tid == 0) ? 0 : sums[tid - 1];
  for (int i = start; i < end; ++i) {
    off[i] = run; pos[i] = run; run += deg[i];
  }
  if (tid == 1023) off[NNODES] = sums[1023];
}
__global__ void csr_fill(const int* __restrict__ ei, int* __restrict__ pos,
                         int* __restrict__ eids) {
  int e = blockIdx.x * blockDim.x + threadIdx.x;
  if (e >= NEDGES) return;
  int p = atomicAdd(&pos[ei[NEDGES + e]], 1);
  eids[p] = e;
}

// ---------- edge attention logits ----------
template<int H, int C, typename TL, typename TR>
__global__ __launch_bounds__(256) void edge_att(
    const int* __restrict__ ei, const TL* __restrict__ xl,
    const TR* __restrict__ xr, const float* __restrict__ att,
    float* __restrict__ ebuf) {
  constexpr int HC = H * C;
  constexpr int CPL = HC / 64;      // channels per lane
  constexpr int GROUP = C / CPL;    // lanes per head
  const int wave = (blockIdx.x * blockDim.x + threadIdx.x) >> 6;
  const int lane = threadIdx.x & 63;
  if (wave >= NEDGES) return;
  const int src = ei[wave];
  const int dst = ei[NEDGES + wave];
  const TL* pl = xl + (size_t)src * HC + lane * CPL;
  const TR* pr = xr + (size_t)dst * HC + lane * CPL;
  const float* pa = att + lane * CPL;
  float sum = 0.f;
  #pragma unroll
  for (int c = 0; c < CPL; ++c) {
    float z = ldf(&pl[c]) + ldf(&pr[c]);
    z = (z > 0.f) ? z : 0.2f * z;
    sum += z * pa[c];
  }
  #pragma unroll
  for (int off = 1; off < GROUP; off <<= 1)
    sum += __shfl_xor(sum, off, 64);
  if ((lane & (GROUP - 1)) == 0)
    ebuf[(size_t)wave * H + lane / GROUP] = sum;
}

// ---------- CSR aggregation: softmax + weighted sum, one wave per node ----------
template<int H, int C, typename TL, bool ELU>
__global__ __launch_bounds__(256) void csr_aggregate(
    const int* __restrict__ off, const int* __restrict__ eids,
    const int* __restrict__ ei, const TL* __restrict__ xl,
    const float* __restrict__ ebuf, const float* __restrict__ bias,
    float* __restrict__ out) {
  constexpr int HC = H * C;
  constexpr int CPL = HC / 64;
  constexpr int GROUP = C / CPL;
  const int n = (blockIdx.x * blockDim.x + threadIdx.x) >> 6;
  const int lane = threadIdx.x & 63;
  if (n >= NNODES) return;
  const int h = lane / GROUP;
  const int s0 = off[n], s1 = off[n + 1];
  float m = -1e30f;
  for (int i = s0; i < s1; ++i)
    m = fmaxf(m, ebuf[(size_t)eids[i] * H + h]);
  float s = 0.f;
  for (int i = s0; i < s1; ++i)
    s += __expf(ebuf[(size_t)eids[i] * H + h] - m);
  const float inv = 1.f / (s + 1e-16f);
  float acc[CPL] = {};
  for (int i = s0; i < s1; ++i) {
    const int eid = eids[i];
    const int src = ei[eid];
    const float alpha = __expf(ebuf[(size_t)eid * H + h] - m) * inv;
    const TL* pl = xl + (size_t)src * HC + lane * CPL;
    #pragma unroll
    for (int c = 0; c < CPL; ++c) acc[c] += alpha * ldf(&pl[c]);
  }
  float* po = out + (size_t)n * HC + lane * CPL;
  #pragma unroll
  for (int c = 0; c < CPL; ++c) {
    float v = acc[c] + bias[lane * CPL + c];
    if (ELU) v = v > 0.f ? v : (__expf(v) - 1.f);
    po[c] = v;
  }
}

// ---------- emergency: report ws_size via absmax ----------
__global__ void report_ws(float* __restrict__ out, float v) { out[0] = v; }

// ---------- pipeline ----------
template<typename TL, typename TR>
static void run_pipeline(const float* x, const int* ei, void* const* d_in,
                         float* out, char* ws, hipStream_t stream) {
  float* acc = (float*)ws;
  size_t off_b = 102400000;                     // N*512*4
  TL* xlb = (TL*)(ws + off_b); off_b += (size_t)NNODES * 512 * sizeof(TL);
  TR* xrb = (TR*)(ws + off_b); off_b += (size_t)NNODES * 512 * sizeof(TR);
  float* ebuf = (float*)(ws + off_b);
  int* coff = (int*)(ws + off_b + 3200000);
  int* cpos = (int*)(ws + off_b + 3400004);
  int* cdeg = (int*)(ws + off_b + 3600004);
  int* eids = (int*)(ws + off_b + 3800004);

  // Build CSR (by dst) once; reused by all 4 layers.
  csr_zero<<<(NNODES + 255) / 256, 256, 0, stream>>>(cdeg);
  csr_hist<<<(NEDGES + 255) / 256, 256, 0, stream>>>(ei, cdeg);
  csr_scan<<<1, 1024, 0, stream>>>(cdeg, coff, cpos);
  csr_fill<<<(NEDGES + 255) / 256, 256, 0, stream>>>(ei, cpos, eids);

  const int egrid = (NEDGES * 64 + 255) / 256;   // one wave per edge
  const int ngrid = (NNODES * 64 + 255) / 256;   // one wave per node

  for (int layer = 0; layer < 4; ++layer) {
    const int base = 2 + layer * 6;
    const float* Wl  = (const float*)d_in[base + 0];
    const float* bl  = (const float*)d_in[base + 1];
    const float* Wr  = (const float*)d_in[base + 2];
    const float* br  = (const float*)d_in[base + 3];
    const float* att = (const float*)d_in[base + 4];
    const float* b   = (const float*)d_in[base + 5];

    const float* h_in = (layer == 0) ? x : acc;
    const int K  = (layer == 0) ? 128 : 512;
    const int HC = (layer == 3) ? 64 : 512;

    dim3 ggrid((NNODES + 63) / 64, HC / 64);
    gemm_bias<TL><<<ggrid, 256, 0, stream>>>(h_in, Wl, bl, xlb, NNODES, K, HC);
    gemm_bias<TR><<<ggrid, 256, 0, stream>>>(h_in, Wr, br, xrb, NNODES, K, HC);

    if (layer < 3) {
      edge_att<4, 128, TL, TR><<<egrid, 256, 0, stream>>>(ei, xlb, xrb, att, ebuf);
      csr_aggregate<4, 128, TL, true><<<ngrid, 256, 0, stream>>>(
          coff, eids, ei, xlb, ebuf, b, acc);
    } else {
      edge_att<1, 64, TL, TR><<<egrid, 256, 0, stream>>>(ei, xlb, xrb, att, ebuf);
      csr_aggregate<1, 64, TL, false><<<ngrid, 256, 0, stream>>>(
          coff, eids, ei, xlb, ebuf, b, out);
    }
  }
}

// ---------- orchestration ----------
extern "C" void kernel_launch(void* const* d_in, const int* in_sizes, int n_in,
                              void* d_out, int out_size, void* d_ws, size_t ws_size,
                              hipStream_t stream) {
  const float* x  = (const float*)d_in[0];
  const int*   ei = (const int*)d_in[1];
  float* out = (float*)d_out;
  char* ws = (char*)d_ws;

  const size_t accB = 102400000ull;   // N*512*4
  const size_t f32B = 102400000ull;   // per fp32 xl/xr buffer
  const size_t b16B = 51200000ull;    // per bf16 xl/xr buffer
  const size_t tailB = 4800000ull;    // ebuf + CSR

  if (ws_size >= accB + 2 * f32B + tailB) {
    run_pipeline<float, float>(x, ei, d_in, out, ws, stream);
  } else if (ws_size >= accB + f32B + b16B + tailB) {
    run_pipeline<float, bf16>(x, ei, d_in, out, ws, stream);
  } else if (ws_size >= accB + 2 * b16B + tailB) {
    run_pipeline<bf16, bf16>(x, ei, d_in, out, ws, stream);
  } else {
    report_ws<<<1, 1, 0, stream>>>(out, (float)ws_size);
  }
}

// Round 5
// 1188.429 us; speedup vs baseline: 9.6984x; 2.6577x over previous
//
#include <hip/hip_runtime.h>
#include <math.h>

#define NNODES 50000
#define NEDGES 200000

typedef unsigned short ushort_t;
using frag8 = __attribute__((ext_vector_type(8))) short;   // 8 x bf16
using facc4 = __attribute__((ext_vector_type(4))) float;   // 4 x f32

// ---------- bf16 helpers (bit-level, RNE) ----------
static __device__ __forceinline__ ushort_t f2b(float f) {
  union { float f; unsigned u; } v; v.f = f;
  unsigned r = v.u + 0x7FFFu + ((v.u >> 16) & 1u);
  return (ushort_t)(r >> 16);
}
static __device__ __forceinline__ float b2f(unsigned hi) {
  return __uint_as_float(hi << 16);
}

// ---------- weight transpose + cast: Wt[c][k] = bf16(W[k][c]) ----------
__global__ void wt_prep(const float* __restrict__ W, ushort_t* __restrict__ Wt,
                        int K, int Mo) {
  int t = blockIdx.x * 256 + threadIdx.x;
  if (t >= K * Mo) return;
  int c = t / K, k = t - c * K;
  Wt[t] = f2b(W[(size_t)k * Mo + c]);
}

// ---------- MFMA GEMM: C[N,Mo](bf16) = A[N,K](f32) * W + bias ----------
// A cast to bf16 in staging; Wt is pre-transposed bf16 [Mo][K].
template<int BN>   // 128 or 64
__global__ __launch_bounds__(256) void gemm_mfma(
    const float* __restrict__ A, const ushort_t* __restrict__ Wt,
    const float* __restrict__ bias, ushort_t* __restrict__ C,
    int N, int K, int Mo) {
  constexpr int WR = (BN == 128) ? 2 : 4;   // waves along rows
  constexpr int WC = 4 / WR;                // waves along cols
  constexpr int RF = 128 / (WR * 16);       // 16-row frags per wave
  constexpr int CF = BN / (WC * 16);        // 16-col frags per wave
  __shared__ __align__(16) ushort_t Al[4][128][8];  // [kblock][row][k-in-block]
  __shared__ __align__(16) ushort_t Bl[4][BN][8];
  const int tid = threadIdx.x;
  const int wave = tid >> 6, lane = tid & 63;
  const int wr = wave / WC, wc = wave % WC;
  const int brow = blockIdx.x * 128;
  const int bcol = blockIdx.y * BN;
  const int l15 = lane & 15, l4 = lane >> 4;

  facc4 acc[RF][CF] = {};

  const int arow = tid >> 1, ahalf = tid & 1;
  for (int k0 = 0; k0 < K; k0 += 32) {
    // ---- stage A tile (cast fp32 -> bf16) ----
    {
      const int grow = brow + arow;
      float4 v0, v1, v2, v3;
      if (grow < N) {
        const float4* pa = (const float4*)(A + (size_t)grow * K + k0 + ahalf * 16);
        v0 = pa[0]; v1 = pa[1]; v2 = pa[2]; v3 = pa[3];
      } else {
        v0 = v1 = v2 = v3 = make_float4(0.f, 0.f, 0.f, 0.f);
      }
      int4 w0 = make_int4(
          (int)((unsigned)f2b(v0.x) | ((unsigned)f2b(v0.y) << 16)),
          (int)((unsigned)f2b(v0.z) | ((unsigned)f2b(v0.w) << 16)),
          (int)((unsigned)f2b(v1.x) | ((unsigned)f2b(v1.y) << 16)),
          (int)((unsigned)f2b(v1.z) | ((unsigned)f2b(v1.w) << 16)));
      int4 w1 = make_int4(
          (int)((unsigned)f2b(v2.x) | ((unsigned)f2b(v2.y) << 16)),
          (int)((unsigned)f2b(v2.z) | ((unsigned)f2b(v2.w) << 16)),
          (int)((unsigned)f2b(v3.x) | ((unsigned)f2b(v3.y) << 16)),
          (int)((unsigned)f2b(v3.z) | ((unsigned)f2b(v3.w) << 16)));
      *(int4*)&Al[ahalf * 2 + 0][arow][0] = w0;
      *(int4*)&Al[ahalf * 2 + 1][arow][0] = w1;
    }
    // ---- stage B tile (already bf16, copy) ----
    if (BN == 128 || tid < BN * 2) {
      const int row = tid >> 1, half = tid & 1;
      const ushort_t* pb = Wt + (size_t)(bcol + row) * K + k0 + half * 16;
      int4 u0 = ((const int4*)pb)[0];
      int4 u1 = ((const int4*)pb)[1];
      *(int4*)&Bl[half * 2 + 0][row][0] = u0;
      *(int4*)&Bl[half * 2 + 1][row][0] = u1;
    }
    __syncthreads();
    frag8 af[RF], bfg[CF];
    #pragma unroll
    for (int i = 0; i < RF; ++i)
      af[i] = *(const frag8*)&Al[l4][wr * (RF * 16) + i * 16 + l15][0];
    #pragma unroll
    for (int j = 0; j < CF; ++j)
      bfg[j] = *(const frag8*)&Bl[l4][wc * (CF * 16) + j * 16 + l15][0];
    #pragma unroll
    for (int i = 0; i < RF; ++i)
      #pragma unroll
      for (int j = 0; j < CF; ++j)
        acc[i][j] = __builtin_amdgcn_mfma_f32_16x16x32_bf16(af[i], bfg[j], acc[i][j], 0, 0, 0);
    __syncthreads();
  }
  // ---- epilogue: D row = (lane>>4)*4 + reg, col = lane&15 ----
  #pragma unroll
  for (int j = 0; j < CF; ++j) {
    const int col = bcol + wc * (CF * 16) + j * 16 + l15;
    const float bv = bias[col];
    #pragma unroll
    for (int i = 0; i < RF; ++i) {
      const int rowb = brow + wr * (RF * 16) + i * 16 + l4 * 4;
      #pragma unroll
      for (int r = 0; r < 4; ++r) {
        const int row = rowb + r;
        if (row < N) C[(size_t)row * Mo + col] = f2b(acc[i][j][r] + bv);
      }
    }
  }
}

// ---------- CSR build (by dst) ----------
__global__ void csr_zero(int* __restrict__ deg) {
  int t = blockIdx.x * blockDim.x + threadIdx.x;
  if (t < NNODES) deg[t] = 0;
}
__global__ void csr_hist(const int* __restrict__ ei, int* __restrict__ deg) {
  int e = blockIdx.x * blockDim.x + threadIdx.x;
  if (e >= NEDGES) return;
  atomicAdd(&deg[ei[NEDGES + e]], 1);
}
__global__ __launch_bounds__(1024) void csr_scan(const int* __restrict__ deg,
                                                 int* __restrict__ off,
                                                 int* __restrict__ pos) {
  __shared__ int sums[1024];
  const int tid = threadIdx.x;
  const int chunk = (NNODES + 1023) / 1024;
  const int start = tid * chunk;
  const int end = (start + chunk < NNODES) ? (start + chunk) : NNODES;
  int local = 0;
  for (int i = start; i < end; ++i) local += deg[i];
  sums[tid] = local;
  __syncthreads();
  for (int d = 1; d < 1024; d <<= 1) {
    int v = (tid >= d) ? sums[tid - d] : 0;
    __syncthreads();
    sums[tid] += v;
    __syncthreads();
  }
  int run = (tid == 0) ? 0 : sums[tid - 1];
  for (int i = start; i < end; ++i) {
    off[i] = run; pos[i] = run; run += deg[i];
  }
  if (tid == 1023) off[NNODES] = sums[1023];
}
__global__ void csr_fill(const int* __restrict__ ei, int* __restrict__ pos,
                         int* __restrict__ eids) {
  int e = blockIdx.x * blockDim.x + threadIdx.x;
  if (e >= NEDGES) return;
  int p = atomicAdd(&pos[ei[NEDGES + e]], 1);
  eids[p] = e;
}

// ---------- edge attention logits (bf16 inputs, vectorized) ----------
template<int H, int C>
__global__ __launch_bounds__(256) void edge_att(
    const int* __restrict__ ei, const ushort_t* __restrict__ xl,
    const ushort_t* __restrict__ xr, const float* __restrict__ att,
    float* __restrict__ ebuf) {
  constexpr int HC = H * C;
  constexpr int CPL = HC / 64;
  constexpr int GROUP = C / CPL;
  const int wave = (blockIdx.x * blockDim.x + threadIdx.x) >> 6;
  const int lane = threadIdx.x & 63;
  if (wave >= NEDGES) return;
  const int src = ei[wave];
  const int dst = ei[NEDGES + wave];
  float sum = 0.f;
  if constexpr (CPL == 8) {
    const int4 vl = *(const int4*)(xl + (size_t)src * HC + lane * 8);
    const int4 vr = *(const int4*)(xr + (size_t)dst * HC + lane * 8);
    const float4 a0 = *(const float4*)(att + lane * 8);
    const float4 a1 = *(const float4*)(att + lane * 8 + 4);
    float zl[8] = { b2f((unsigned)vl.x & 0xFFFFu), b2f((unsigned)vl.x >> 16),
                    b2f((unsigned)vl.y & 0xFFFFu), b2f((unsigned)vl.y >> 16),
                    b2f((unsigned)vl.z & 0xFFFFu), b2f((unsigned)vl.z >> 16),
                    b2f((unsigned)vl.w & 0xFFFFu), b2f((unsigned)vl.w >> 16) };
    float zr[8] = { b2f((unsigned)vr.x & 0xFFFFu), b2f((unsigned)vr.x >> 16),
                    b2f((unsigned)vr.y & 0xFFFFu), b2f((unsigned)vr.y >> 16),
                    b2f((unsigned)vr.z & 0xFFFFu), b2f((unsigned)vr.z >> 16),
                    b2f((unsigned)vr.w & 0xFFFFu), b2f((unsigned)vr.w >> 16) };
    float av[8] = { a0.x, a0.y, a0.z, a0.w, a1.x, a1.y, a1.z, a1.w };
    #pragma unroll
    for (int c = 0; c < 8; ++c) {
      float z = zl[c] + zr[c];
      z = (z > 0.f) ? z : 0.2f * z;
      sum += z * av[c];
    }
  } else {
    float z = b2f(xl[(size_t)src * HC + lane]) + b2f(xr[(size_t)dst * HC + lane]);
    z = (z > 0.f) ? z : 0.2f * z;
    sum = z * att[lane];
  }
  #pragma unroll
  for (int off = 1; off < GROUP; off <<= 1)
    sum += __shfl_xor(sum, off, 64);
  if ((lane & (GROUP - 1)) == 0)
    ebuf[(size_t)wave * H + lane / GROUP] = sum;
}

// ---------- CSR aggregation: softmax + weighted gather, one wave/node ----------
template<int H, int C, bool ELU>
__global__ __launch_bounds__(256) void csr_aggregate(
    const int* __restrict__ off, const int* __restrict__ eids,
    const int* __restrict__ ei, const ushort_t* __restrict__ xl,
    const float* __restrict__ ebuf, const float* __restrict__ bias,
    float* __restrict__ out) {
  constexpr int HC = H * C;
  constexpr int CPL = HC / 64;
  constexpr int GROUP = C / CPL;
  const int n = (blockIdx.x * blockDim.x + threadIdx.x) >> 6;
  const int lane = threadIdx.x & 63;
  if (n >= NNODES) return;
  const int h = lane / GROUP;
  const int s0 = off[n], s1 = off[n + 1];
  float m = -1e30f;
  for (int i = s0; i < s1; ++i)
    m = fmaxf(m, ebuf[(size_t)eids[i] * H + h]);
  float s = 0.f;
  for (int i = s0; i < s1; ++i)
    s += __expf(ebuf[(size_t)eids[i] * H + h] - m);
  const float inv = 1.f / (s + 1e-16f);
  float acc[CPL] = {};
  for (int i = s0; i < s1; ++i) {
    const int eid = eids[i];
    const int srcn = ei[eid];
    const float alpha = __expf(ebuf[(size_t)eid * H + h] - m) * inv;
    if constexpr (CPL == 8) {
      const int4 vl = *(const int4*)(xl + (size_t)srcn * HC + lane * 8);
      acc[0] += alpha * b2f((unsigned)vl.x & 0xFFFFu);
      acc[1] += alpha * b2f((unsigned)vl.x >> 16);
      acc[2] += alpha * b2f((unsigned)vl.y & 0xFFFFu);
      acc[3] += alpha * b2f((unsigned)vl.y >> 16);
      acc[4] += alpha * b2f((unsigned)vl.z & 0xFFFFu);
      acc[5] += alpha * b2f((unsigned)vl.z >> 16);
      acc[6] += alpha * b2f((unsigned)vl.w & 0xFFFFu);
      acc[7] += alpha * b2f((unsigned)vl.w >> 16);
    } else {
      acc[0] += alpha * b2f(xl[(size_t)srcn * HC + lane]);
    }
  }
  float* po = out + (size_t)n * HC + lane * CPL;
  #pragma unroll
  for (int c = 0; c < CPL; ++c) {
    float v = acc[c] + bias[lane * CPL + c];
    if (ELU) v = v > 0.f ? v : (__expf(v) - 1.f);
    po[c] = v;
  }
}

// ---------- emergency: report ws_size via absmax ----------
__global__ void report_ws(float* __restrict__ out, float v) { out[0] = v; }

// ---------- orchestration ----------
extern "C" void kernel_launch(void* const* d_in, const int* in_sizes, int n_in,
                              void* d_out, int out_size, void* d_ws, size_t ws_size,
                              hipStream_t stream) {
  const float* x  = (const float*)d_in[0];
  const int*   ei = (const int*)d_in[1];
  float* out = (float*)d_out;
  char* ws = (char*)d_ws;

  // layout (bytes)
  float*    acc  = (float*)(ws);                      // N*512 f32   102,400,000
  ushort_t* xlb  = (ushort_t*)(ws + 102400000ull);    // N*512 bf16   51,200,000
  ushort_t* xrb  = (ushort_t*)(ws + 153600000ull);    // N*512 bf16   51,200,000
  float*    ebuf = (float*)(ws + 204800000ull);       // E*4 f32       3,200,000
  // Wt buffers alias the ebuf region (sequencing makes this safe):
  // WtL needs up to 512*512*2 = 524,288 B -> give it a 1 MiB slot.
  ushort_t* WtL  = (ushort_t*)(ws + 204800000ull);
  ushort_t* WtR  = (ushort_t*)(ws + 205848576ull);    // 204800000 + 1 MiB
  int* coff = (int*)(ws + 208000000ull);
  int* cpos = (int*)(ws + 208200008ull);
  int* cdeg = (int*)(ws + 208400012ull);
  int* eids = (int*)(ws + 208600016ull);              // end 209,400,016

  if (ws_size < 209400016ull) {
    report_ws<<<1, 1, 0, stream>>>(out, (float)ws_size);
    return;
  }

  // CSR by dst, built once
  csr_zero<<<(NNODES + 255) / 256, 256, 0, stream>>>(cdeg);
  csr_hist<<<(NEDGES + 255) / 256, 256, 0, stream>>>(ei, cdeg);
  csr_scan<<<1, 1024, 0, stream>>>(cdeg, coff, cpos);
  csr_fill<<<(NEDGES + 255) / 256, 256, 0, stream>>>(ei, cpos, eids);

  const int egrid = (NEDGES * 64 + 255) / 256;
  const int ngrid = (NNODES * 64 + 255) / 256;

  for (int layer = 0; layer < 4; ++layer) {
    const int base = 2 + layer * 6;
    const float* Wl  = (const float*)d_in[base + 0];
    const float* bl  = (const float*)d_in[base + 1];
    const float* Wr  = (const float*)d_in[base + 2];
    const float* br  = (const float*)d_in[base + 3];
    const float* att = (const float*)d_in[base + 4];
    const float* b   = (const float*)d_in[base + 5];

    const float* h_in = (layer == 0) ? x : acc;
    const int K  = (layer == 0) ? 128 : 512;
    const int Mo = (layer == 3) ? 64 : 512;

    const int wtg = (K * Mo + 255) / 256;
    wt_prep<<<wtg, 256, 0, stream>>>(Wl, WtL, K, Mo);
    wt_prep<<<wtg, 256, 0, stream>>>(Wr, WtR, K, Mo);

    if (layer < 3) {
      dim3 gg((NNODES + 127) / 128, Mo / 128);
      gemm_mfma<128><<<gg, 256, 0, stream>>>(h_in, WtL, bl, xlb, NNODES, K, Mo);
      gemm_mfma<128><<<gg, 256, 0, stream>>>(h_in, WtR, br, xrb, NNODES, K, Mo);
      edge_att<4, 128><<<egrid, 256, 0, stream>>>(ei, xlb, xrb, att, ebuf);
      csr_aggregate<4, 128, true><<<ngrid, 256, 0, stream>>>(
          coff, eids, ei, xlb, ebuf, b, acc);
    } else {
      dim3 gg((NNODES + 127) / 128, 1);
      gemm_mfma<64><<<gg, 256, 0, stream>>>(h_in, WtL, bl, xlb, NNODES, K, Mo);
      gemm_mfma<64><<<gg, 256, 0, stream>>>(h_in, WtR, br, xrb, NNODES, K, Mo);
      edge_att<1, 64><<<egrid, 256, 0, stream>>>(ei, xlb, xrb, att, ebuf);
      csr_aggregate<1, 64, false><<<ngrid, 256, 0, stream>>>(
          coff, eids, ei, xlb, ebuf, b, out);
    }
  }
}

// Round 6
// 808.317 us; speedup vs baseline: 14.2591x; 1.4703x over previous
//
#include <hip/hip_runtime.h>
#include <math.h>

#define NNODES 50000
#define NEDGES 200000

typedef unsigned short ushort_t;
using frag8 = __attribute__((ext_vector_type(8))) short;   // 8 x bf16
using facc4 = __attribute__((ext_vector_type(4))) float;   // 4 x f32

// ---------- bf16 helpers (bit-level, RNE) ----------
static __device__ __forceinline__ ushort_t f2b(float f) {
  union { float f; unsigned u; } v; v.f = f;
  unsigned r = v.u + 0x7FFFu + ((v.u >> 16) & 1u);
  return (ushort_t)(r >> 16);
}
static __device__ __forceinline__ float b2f(unsigned hi) {
  return __uint_as_float(hi << 16);
}
static __device__ __forceinline__ void unpack8(const int4 v, float* f) {
  f[0] = b2f((unsigned)v.x & 0xFFFFu); f[1] = b2f((unsigned)v.x >> 16);
  f[2] = b2f((unsigned)v.y & 0xFFFFu); f[3] = b2f((unsigned)v.y >> 16);
  f[4] = b2f((unsigned)v.z & 0xFFFFu); f[5] = b2f((unsigned)v.z >> 16);
  f[6] = b2f((unsigned)v.w & 0xFFFFu); f[7] = b2f((unsigned)v.w >> 16);
}

// ---------- weight transpose + cast (L and R fused): Wt[c][k] = bf16(W[k][c]) ----------
__global__ void wt_prep2(const float* __restrict__ Wl, const float* __restrict__ Wr,
                         ushort_t* __restrict__ WtL, ushort_t* __restrict__ WtR,
                         int K, int Mo) {
  int t = blockIdx.x * 256 + threadIdx.x;
  const int tot = K * Mo;
  if (t >= 2 * tot) return;
  const float* W = (t < tot) ? Wl : Wr;
  ushort_t* Wt = (t < tot) ? WtL : WtR;
  int u = (t < tot) ? t : t - tot;
  int c = u / K, k = u - c * K;
  Wt[u] = f2b(W[(size_t)k * Mo + c]);
}

// ---------- MFMA GEMM: C[N,Mo](bf16) = A[N,K](f32) * W + bias ----------
template<int BN>   // 128 or 64
__global__ __launch_bounds__(256) void gemm_mfma(
    const float* __restrict__ A, const ushort_t* __restrict__ Wt,
    const float* __restrict__ bias, ushort_t* __restrict__ C,
    int N, int K, int Mo) {
  constexpr int WR = (BN == 128) ? 2 : 4;
  constexpr int WC = 4 / WR;
  constexpr int RF = 128 / (WR * 16);
  constexpr int CF = BN / (WC * 16);
  __shared__ __align__(16) ushort_t Al[4][128][8];  // [kblock][row][k-in-block]
  __shared__ __align__(16) ushort_t Bl[4][BN][8];
  const int tid = threadIdx.x;
  const int wave = tid >> 6, lane = tid & 63;
  const int wr = wave / WC, wc = wave % WC;
  const int brow = blockIdx.x * 128;
  const int bcol = blockIdx.y * BN;
  const int l15 = lane & 15, l4 = lane >> 4;

  facc4 acc[RF][CF] = {};

  const int arow = tid >> 1, ahalf = tid & 1;
  for (int k0 = 0; k0 < K; k0 += 32) {
    {
      const int grow = brow + arow;
      float4 v0, v1, v2, v3;
      if (grow < N) {
        const float4* pa = (const float4*)(A + (size_t)grow * K + k0 + ahalf * 16);
        v0 = pa[0]; v1 = pa[1]; v2 = pa[2]; v3 = pa[3];
      } else {
        v0 = v1 = v2 = v3 = make_float4(0.f, 0.f, 0.f, 0.f);
      }
      int4 w0 = make_int4(
          (int)((unsigned)f2b(v0.x) | ((unsigned)f2b(v0.y) << 16)),
          (int)((unsigned)f2b(v0.z) | ((unsigned)f2b(v0.w) << 16)),
          (int)((unsigned)f2b(v1.x) | ((unsigned)f2b(v1.y) << 16)),
          (int)((unsigned)f2b(v1.z) | ((unsigned)f2b(v1.w) << 16)));
      int4 w1 = make_int4(
          (int)((unsigned)f2b(v2.x) | ((unsigned)f2b(v2.y) << 16)),
          (int)((unsigned)f2b(v2.z) | ((unsigned)f2b(v2.w) << 16)),
          (int)((unsigned)f2b(v3.x) | ((unsigned)f2b(v3.y) << 16)),
          (int)((unsigned)f2b(v3.z) | ((unsigned)f2b(v3.w) << 16)));
      *(int4*)&Al[ahalf * 2 + 0][arow][0] = w0;
      *(int4*)&Al[ahalf * 2 + 1][arow][0] = w1;
    }
    if (BN == 128 || tid < BN * 2) {
      const int row = tid >> 1, half = tid & 1;
      const ushort_t* pb = Wt + (size_t)(bcol + row) * K + k0 + half * 16;
      int4 u0 = ((const int4*)pb)[0];
      int4 u1 = ((const int4*)pb)[1];
      *(int4*)&Bl[half * 2 + 0][row][0] = u0;
      *(int4*)&Bl[half * 2 + 1][row][0] = u1;
    }
    __syncthreads();
    frag8 af[RF], bfg[CF];
    #pragma unroll
    for (int i = 0; i < RF; ++i)
      af[i] = *(const frag8*)&Al[l4][wr * (RF * 16) + i * 16 + l15][0];
    #pragma unroll
    for (int j = 0; j < CF; ++j)
      bfg[j] = *(const frag8*)&Bl[l4][wc * (CF * 16) + j * 16 + l15][0];
    #pragma unroll
    for (int i = 0; i < RF; ++i)
      #pragma unroll
      for (int j = 0; j < CF; ++j)
        acc[i][j] = __builtin_amdgcn_mfma_f32_16x16x32_bf16(af[i], bfg[j], acc[i][j], 0, 0, 0);
    __syncthreads();
  }
  #pragma unroll
  for (int j = 0; j < CF; ++j) {
    const int col = bcol + wc * (CF * 16) + j * 16 + l15;
    const float bv = bias[col];
    #pragma unroll
    for (int i = 0; i < RF; ++i) {
      const int rowb = brow + wr * (RF * 16) + i * 16 + l4 * 4;
      #pragma unroll
      for (int r = 0; r < 4; ++r) {
        const int row = rowb + r;
        if (row < N) C[(size_t)row * Mo + col] = f2b(acc[i][j][r] + bv);
      }
    }
  }
}

// ---------- CSR build (by dst) ----------
__global__ void csr_zero(int* __restrict__ deg) {
  int t = blockIdx.x * blockDim.x + threadIdx.x;
  if (t < NNODES) deg[t] = 0;
}
__global__ void csr_hist(const int* __restrict__ ei, int* __restrict__ deg) {
  int e = blockIdx.x * blockDim.x + threadIdx.x;
  if (e >= NEDGES) return;
  atomicAdd(&deg[ei[NEDGES + e]], 1);
}

// multi-block exclusive scan of deg -> off (and pos copy)
#define SCAN_TPB 256
#define SCAN_EPT 4
#define SCAN_CHUNK (SCAN_TPB * SCAN_EPT)                       // 1024
#define SCAN_BLK ((NNODES + SCAN_CHUNK - 1) / SCAN_CHUNK)      // 49

__global__ __launch_bounds__(SCAN_TPB) void scan_k1(const int* __restrict__ deg,
                                                    int* __restrict__ bsum) {
  __shared__ int sd[SCAN_TPB];
  const int tid = threadIdx.x;
  const int tbase = blockIdx.x * SCAN_CHUNK + tid * SCAN_EPT;
  int s = 0;
  #pragma unroll
  for (int j = 0; j < SCAN_EPT; ++j) {
    int idx = tbase + j;
    if (idx < NNODES) s += deg[idx];
  }
  sd[tid] = s;
  __syncthreads();
  for (int d = SCAN_TPB / 2; d > 0; d >>= 1) {
    if (tid < d) sd[tid] += sd[tid + d];
    __syncthreads();
  }
  if (tid == 0) bsum[blockIdx.x] = sd[0];
}

__global__ __launch_bounds__(64) void scan_k2(const int* __restrict__ bsum,
                                              int* __restrict__ bpref,
                                              int* __restrict__ off) {
  __shared__ int sd[64];
  const int tid = threadIdx.x;
  sd[tid] = (tid < SCAN_BLK) ? bsum[tid] : 0;
  __syncthreads();
  for (int d = 1; d < 64; d <<= 1) {
    int t = (tid >= d) ? sd[tid - d] : 0;
    __syncthreads();
    sd[tid] += t;
    __syncthreads();
  }
  if (tid < SCAN_BLK) bpref[tid] = (tid == 0) ? 0 : sd[tid - 1];
  if (tid == 0) off[NNODES] = NEDGES;
}

__global__ __launch_bounds__(SCAN_TPB) void scan_k3(const int* __restrict__ deg,
                                                    const int* __restrict__ bpref,
                                                    int* __restrict__ off,
                                                    int* __restrict__ pos) {
  __shared__ int sd[SCAN_TPB];
  const int tid = threadIdx.x;
  const int tbase = blockIdx.x * SCAN_CHUNK + tid * SCAN_EPT;
  int v[SCAN_EPT];
  int s = 0;
  #pragma unroll
  for (int j = 0; j < SCAN_EPT; ++j) {
    int idx = tbase + j;
    v[j] = (idx < NNODES) ? deg[idx] : 0;
    s += v[j];
  }
  sd[tid] = s;
  __syncthreads();
  for (int d = 1; d < SCAN_TPB; d <<= 1) {
    int t = (tid >= d) ? sd[tid - d] : 0;
    __syncthreads();
    sd[tid] += t;
    __syncthreads();
  }
  int run = bpref[blockIdx.x] + ((tid == 0) ? 0 : sd[tid - 1]);
  #pragma unroll
  for (int j = 0; j < SCAN_EPT; ++j) {
    int idx = tbase + j;
    if (idx < NNODES) { off[idx] = run; pos[idx] = run; run += v[j]; }
  }
}

__global__ void csr_fill(const int* __restrict__ ei, int* __restrict__ pos,
                         int* __restrict__ eids) {
  int e = blockIdx.x * blockDim.x + threadIdx.x;
  if (e >= NEDGES) return;
  int p = atomicAdd(&pos[ei[NEDGES + e]], 1);
  eids[p] = e;
}

// ---------- fused attention + online-softmax aggregation, one wave/node ----------
template<int H, int C, bool ELU>
__global__ __launch_bounds__(256) void csr_fused(
    const int* __restrict__ off, const int* __restrict__ eids,
    const int* __restrict__ ei, const ushort_t* __restrict__ xl,
    const ushort_t* __restrict__ xr, const float* __restrict__ att,
    const float* __restrict__ bias, float* __restrict__ out) {
  constexpr int HC = H * C;
  constexpr int CPL = HC / 64;     // channels per lane
  constexpr int GROUP = C / CPL;   // lanes per head
  const int n = (blockIdx.x * blockDim.x + threadIdx.x) >> 6;
  const int lane = threadIdx.x & 63;
  if (n >= NNODES) return;
  const int s0 = off[n], s1 = off[n + 1];

  // per-lane slices of xr[n], att
  float xrr[CPL], atr[CPL];
  if constexpr (CPL == 8) {
    unpack8(*(const int4*)(xr + (size_t)n * HC + lane * 8), xrr);
    const float4 a0 = *(const float4*)(att + lane * 8);
    const float4 a1 = *(const float4*)(att + lane * 8 + 4);
    atr[0] = a0.x; atr[1] = a0.y; atr[2] = a0.z; atr[3] = a0.w;
    atr[4] = a1.x; atr[5] = a1.y; atr[6] = a1.z; atr[7] = a1.w;
  } else {
    xrr[0] = b2f(xr[(size_t)n * HC + lane]);
    atr[0] = att[lane];
  }

  float m = -1e30f, s = 0.f;
  float acc[CPL] = {};
  for (int i = s0; i < s1; ++i) {
    const int eid = eids[i];
    const int srcn = ei[eid];
    float zl[CPL];
    if constexpr (CPL == 8)
      unpack8(*(const int4*)(xl + (size_t)srcn * HC + lane * 8), zl);
    else
      zl[0] = b2f(xl[(size_t)srcn * HC + lane]);
    // logit for this head
    float e = 0.f;
    #pragma unroll
    for (int c = 0; c < CPL; ++c) {
      float z = zl[c] + xrr[c];
      z = (z > 0.f) ? z : 0.2f * z;
      e += z * atr[c];
    }
    #pragma unroll
    for (int o = 1; o < GROUP; o <<= 1)
      e += __shfl_xor(e, o, 64);
    // online softmax update
    if (e > m) {
      const float scale = __expf(m - e);   // first edge: exp(-inf)=0
      s *= scale;
      #pragma unroll
      for (int c = 0; c < CPL; ++c) acc[c] *= scale;
      m = e;
    }
    const float w = __expf(e - m);
    s += w;
    #pragma unroll
    for (int c = 0; c < CPL; ++c) acc[c] += w * zl[c];
  }
  const float inv = 1.f / (s + 1e-16f);
  float* po = out + (size_t)n * HC + lane * CPL;
  #pragma unroll
  for (int c = 0; c < CPL; ++c) {
    float v = acc[c] * inv + bias[lane * CPL + c];
    if (ELU) v = v > 0.f ? v : (__expf(v) - 1.f);
    po[c] = v;
  }
}

// ---------- emergency: report ws_size via absmax ----------
__global__ void report_ws(float* __restrict__ out, float v) { out[0] = v; }

// ---------- orchestration ----------
extern "C" void kernel_launch(void* const* d_in, const int* in_sizes, int n_in,
                              void* d_out, int out_size, void* d_ws, size_t ws_size,
                              hipStream_t stream) {
  const float* x  = (const float*)d_in[0];
  const int*   ei = (const int*)d_in[1];
  float* out = (float*)d_out;
  char* ws = (char*)d_ws;

  // layout (bytes)
  float*    acc  = (float*)(ws);                      // N*512 f32   102,400,000
  ushort_t* xlb  = (ushort_t*)(ws + 102400000ull);    // N*512 bf16   51,200,000
  ushort_t* xrb  = (ushort_t*)(ws + 153600000ull);    // N*512 bf16   51,200,000
  ushort_t* WtL  = (ushort_t*)(ws + 204800000ull);    // <=512KB, 1MiB slot
  ushort_t* WtR  = (ushort_t*)(ws + 205848576ull);    // 1MiB slot
  int* bsum  = (int*)(ws + 207000000ull);             // 49 ints
  int* bpref = (int*)(ws + 207001024ull);             // 49 ints
  int* coff  = (int*)(ws + 208000000ull);             // N+1
  int* cpos  = (int*)(ws + 208200008ull);             // N
  int* cdeg  = (int*)(ws + 208400012ull);             // N
  int* eids  = (int*)(ws + 208600016ull);             // E  (end 209,400,016)

  if (ws_size < 209400016ull) {
    report_ws<<<1, 1, 0, stream>>>(out, (float)ws_size);
    return;
  }

  // CSR by dst, built once
  csr_zero<<<(NNODES + 255) / 256, 256, 0, stream>>>(cdeg);
  csr_hist<<<(NEDGES + 255) / 256, 256, 0, stream>>>(ei, cdeg);
  scan_k1<<<SCAN_BLK, SCAN_TPB, 0, stream>>>(cdeg, bsum);
  scan_k2<<<1, 64, 0, stream>>>(bsum, bpref, coff);
  scan_k3<<<SCAN_BLK, SCAN_TPB, 0, stream>>>(cdeg, bpref, coff, cpos);
  csr_fill<<<(NEDGES + 255) / 256, 256, 0, stream>>>(ei, cpos, eids);

  const int ngrid = (NNODES * 64 + 255) / 256;

  for (int layer = 0; layer < 4; ++layer) {
    const int base = 2 + layer * 6;
    const float* Wl  = (const float*)d_in[base + 0];
    const float* bl  = (const float*)d_in[base + 1];
    const float* Wr  = (const float*)d_in[base + 2];
    const float* br  = (const float*)d_in[base + 3];
    const float* att = (const float*)d_in[base + 4];
    const float* b   = (const float*)d_in[base + 5];

    const float* h_in = (layer == 0) ? x : acc;
    const int K  = (layer == 0) ? 128 : 512;
    const int Mo = (layer == 3) ? 64 : 512;

    wt_prep2<<<(2 * K * Mo + 255) / 256, 256, 0, stream>>>(Wl, Wr, WtL, WtR, K, Mo);

    if (layer < 3) {
      dim3 gg((NNODES + 127) / 128, Mo / 128);
      gemm_mfma<128><<<gg, 256, 0, stream>>>(h_in, WtL, bl, xlb, NNODES, K, Mo);
      gemm_mfma<128><<<gg, 256, 0, stream>>>(h_in, WtR, br, xrb, NNODES, K, Mo);
      csr_fused<4, 128, true><<<ngrid, 256, 0, stream>>>(
          coff, eids, ei, xlb, xrb, att, b, acc);
    } else {
      dim3 gg((NNODES + 127) / 128, 1);
      gemm_mfma<64><<<gg, 256, 0, stream>>>(h_in, WtL, bl, xlb, NNODES, K, Mo);
      gemm_mfma<64><<<gg, 256, 0, stream>>>(h_in, WtR, br, xrb, NNODES, K, Mo);
      csr_fused<1, 64, false><<<ngrid, 256, 0, stream>>>(
          coff, eids, ei, xlb, xrb, att, b, out);
    }
  }
}

// Round 7
// 635.930 us; speedup vs baseline: 18.1245x; 1.2711x over previous
//
#include <hip/hip_runtime.h>
#include <math.h>

#define NNODES 50000
#define NEDGES 200000

typedef unsigned short ushort_t;
using frag8 = __attribute__((ext_vector_type(8))) short;   // 8 x bf16
using facc4 = __attribute__((ext_vector_type(4))) float;   // 4 x f32

// ---------- bf16 helpers (bit-level, RNE) ----------
static __device__ __forceinline__ ushort_t f2b(float f) {
  union { float f; unsigned u; } v; v.f = f;
  unsigned r = v.u + 0x7FFFu + ((v.u >> 16) & 1u);
  return (ushort_t)(r >> 16);
}
static __device__ __forceinline__ float b2f(unsigned hi) {
  return __uint_as_float(hi << 16);
}
static __device__ __forceinline__ void unpack8(const int4 v, float* f) {
  f[0] = b2f((unsigned)v.x & 0xFFFFu); f[1] = b2f((unsigned)v.x >> 16);
  f[2] = b2f((unsigned)v.y & 0xFFFFu); f[3] = b2f((unsigned)v.y >> 16);
  f[4] = b2f((unsigned)v.z & 0xFFFFu); f[5] = b2f((unsigned)v.z >> 16);
  f[6] = b2f((unsigned)v.w & 0xFFFFu); f[7] = b2f((unsigned)v.w >> 16);
}
static __device__ __forceinline__ void stf(float* p, float v) { *p = v; }
static __device__ __forceinline__ void stf(ushort_t* p, float v) { *p = f2b(v); }

// ---------- cast x (fp32) -> bf16, 8 elems/thread ----------
__global__ void cast_x(const float* __restrict__ x, ushort_t* __restrict__ xb, int total8) {
  int t = blockIdx.x * 256 + threadIdx.x;
  if (t >= total8) return;
  const float4* p = (const float4*)(x + (size_t)t * 8);
  float4 a = p[0], b = p[1];
  int4 w = make_int4(
      (int)((unsigned)f2b(a.x) | ((unsigned)f2b(a.y) << 16)),
      (int)((unsigned)f2b(a.z) | ((unsigned)f2b(a.w) << 16)),
      (int)((unsigned)f2b(b.x) | ((unsigned)f2b(b.y) << 16)),
      (int)((unsigned)f2b(b.z) | ((unsigned)f2b(b.w) << 16)));
  *(int4*)(xb + (size_t)t * 8) = w;
}

// ---------- weight transpose + cast (L and R into one buffer) ----------
// WtLR[c][k] for c in [0,2*Mo): c<Mo -> Wl col c, else Wr col c-Mo.
__global__ void wt_prep2(const float* __restrict__ Wl, const float* __restrict__ Wr,
                         ushort_t* __restrict__ WtLR, int K, int Mo) {
  int t = blockIdx.x * 256 + threadIdx.x;
  const int tot = K * Mo;
  if (t >= 2 * tot) return;
  const float* W = (t < tot) ? Wl : Wr;
  int u = (t < tot) ? t : t - tot;
  int c = u / K, k = u - c * K;
  WtLR[t] = f2b(W[(size_t)k * Mo + c]);
}

// ---------- fused MFMA GEMM: [xl|xr][N,Mo](bf16) = A[N,K](bf16) * WtLR + bias ----------
// 128x128 tile over (rows, 2*Mo cols). gridDim.x = 2*Mo/128 (col-fastest for A reuse).
__global__ __launch_bounds__(256) void gemm2_mfma(
    const ushort_t* __restrict__ A, const ushort_t* __restrict__ WtLR,
    const float* __restrict__ bl, const float* __restrict__ br,
    ushort_t* __restrict__ xlb, ushort_t* __restrict__ xrb,
    int N, int K, int Mo) {
  __shared__ __align__(16) ushort_t Al[4][128][8];  // [kblock][row][k-in-block]
  __shared__ __align__(16) ushort_t Bl[4][128][8];
  const int tid = threadIdx.x;
  const int wave = tid >> 6, lane = tid & 63;
  const int wr = wave >> 1, wc = wave & 1;          // 2x2 waves
  const int brow = blockIdx.y * 128;
  const int bcol = blockIdx.x * 128;                // within 2*Mo
  const int l15 = lane & 15, l4 = lane >> 4;

  facc4 acc[4][4] = {};

  const int srow = tid >> 1;          // 0..127 (row for A, col for B)
  const int skb  = (tid & 1) * 2;     // kblock 0 or 2 (handles 2 consecutive)
  for (int k0 = 0; k0 < K; k0 += 32) {
    {
      const int grow = brow + srow;
      int4 a0, a1;
      if (grow < N) {
        const int4* pa = (const int4*)(A + (size_t)grow * K + k0 + skb * 8);
        a0 = pa[0]; a1 = pa[1];
      } else {
        a0 = a1 = make_int4(0, 0, 0, 0);
      }
      *(int4*)&Al[skb + 0][srow][0] = a0;
      *(int4*)&Al[skb + 1][srow][0] = a1;
      const int4* pb = (const int4*)(WtLR + (size_t)(bcol + srow) * K + k0 + skb * 8);
      int4 b0 = pb[0], b1 = pb[1];
      *(int4*)&Bl[skb + 0][srow][0] = b0;
      *(int4*)&Bl[skb + 1][srow][0] = b1;
    }
    __syncthreads();
    frag8 af[4], bfg[4];
    #pragma unroll
    for (int i = 0; i < 4; ++i)
      af[i] = *(const frag8*)&Al[l4][wr * 64 + i * 16 + l15][0];
    #pragma unroll
    for (int j = 0; j < 4; ++j)
      bfg[j] = *(const frag8*)&Bl[l4][wc * 64 + j * 16 + l15][0];
    #pragma unroll
    for (int i = 0; i < 4; ++i)
      #pragma unroll
      for (int j = 0; j < 4; ++j)
        acc[i][j] = __builtin_amdgcn_mfma_f32_16x16x32_bf16(af[i], bfg[j], acc[i][j], 0, 0, 0);
    __syncthreads();
  }
  // epilogue: D row=(lane>>4)*4+r, col=lane&15; route col -> xl or xr
  #pragma unroll
  for (int j = 0; j < 4; ++j) {
    const int col2 = bcol + wc * 64 + j * 16 + l15;   // in [0, 2*Mo)
    const bool isL = col2 < Mo;
    const int col = isL ? col2 : col2 - Mo;
    const float bv = isL ? bl[col] : br[col];
    ushort_t* dst = isL ? xlb : xrb;
    #pragma unroll
    for (int i = 0; i < 4; ++i) {
      const int rowb = brow + wr * 64 + i * 16 + l4 * 4;
      #pragma unroll
      for (int r = 0; r < 4; ++r) {
        const int row = rowb + r;
        if (row < N) dst[(size_t)row * Mo + col] = f2b(acc[i][j][r] + bv);
      }
    }
  }
}

// ---------- CSR build (by dst) ----------
__global__ void csr_zero(int* __restrict__ deg) {
  int t = blockIdx.x * blockDim.x + threadIdx.x;
  if (t < NNODES) deg[t] = 0;
}
__global__ void csr_hist(const int* __restrict__ ei, int* __restrict__ deg) {
  int e = blockIdx.x * blockDim.x + threadIdx.x;
  if (e >= NEDGES) return;
  atomicAdd(&deg[ei[NEDGES + e]], 1);
}

#define SCAN_TPB 256
#define SCAN_EPT 4
#define SCAN_CHUNK (SCAN_TPB * SCAN_EPT)                       // 1024
#define SCAN_BLK ((NNODES + SCAN_CHUNK - 1) / SCAN_CHUNK)      // 49

__global__ __launch_bounds__(SCAN_TPB) void scan_k1(const int* __restrict__ deg,
                                                    int* __restrict__ bsum) {
  __shared__ int sd[SCAN_TPB];
  const int tid = threadIdx.x;
  const int tbase = blockIdx.x * SCAN_CHUNK + tid * SCAN_EPT;
  int s = 0;
  #pragma unroll
  for (int j = 0; j < SCAN_EPT; ++j) {
    int idx = tbase + j;
    if (idx < NNODES) s += deg[idx];
  }
  sd[tid] = s;
  __syncthreads();
  for (int d = SCAN_TPB / 2; d > 0; d >>= 1) {
    if (tid < d) sd[tid] += sd[tid + d];
    __syncthreads();
  }
  if (tid == 0) bsum[blockIdx.x] = sd[0];
}

__global__ __launch_bounds__(64) void scan_k2(const int* __restrict__ bsum,
                                              int* __restrict__ bpref,
                                              int* __restrict__ off) {
  __shared__ int sd[64];
  const int tid = threadIdx.x;
  sd[tid] = (tid < SCAN_BLK) ? bsum[tid] : 0;
  __syncthreads();
  for (int d = 1; d < 64; d <<= 1) {
    int t = (tid >= d) ? sd[tid - d] : 0;
    __syncthreads();
    sd[tid] += t;
    __syncthreads();
  }
  if (tid < SCAN_BLK) bpref[tid] = (tid == 0) ? 0 : sd[tid - 1];
  if (tid == 0) off[NNODES] = NEDGES;
}

__global__ __launch_bounds__(SCAN_TPB) void scan_k3(const int* __restrict__ deg,
                                                    const int* __restrict__ bpref,
                                                    int* __restrict__ off,
                                                    int* __restrict__ pos) {
  __shared__ int sd[SCAN_TPB];
  const int tid = threadIdx.x;
  const int tbase = blockIdx.x * SCAN_CHUNK + tid * SCAN_EPT;
  int v[SCAN_EPT];
  int s = 0;
  #pragma unroll
  for (int j = 0; j < SCAN_EPT; ++j) {
    int idx = tbase + j;
    v[j] = (idx < NNODES) ? deg[idx] : 0;
    s += v[j];
  }
  sd[tid] = s;
  __syncthreads();
  for (int d = 1; d < SCAN_TPB; d <<= 1) {
    int t = (tid >= d) ? sd[tid - d] : 0;
    __syncthreads();
    sd[tid] += t;
    __syncthreads();
  }
  int run = bpref[blockIdx.x] + ((tid == 0) ? 0 : sd[tid - 1]);
  #pragma unroll
  for (int j = 0; j < SCAN_EPT; ++j) {
    int idx = tbase + j;
    if (idx < NNODES) { off[idx] = run; pos[idx] = run; run += v[j]; }
  }
}

__global__ void csr_fill(const int* __restrict__ ei, int* __restrict__ pos,
                         int* __restrict__ eids) {
  int e = blockIdx.x * blockDim.x + threadIdx.x;
  if (e >= NEDGES) return;
  int p = atomicAdd(&pos[ei[NEDGES + e]], 1);
  eids[p] = e;
}

// ---------- fused attention + online-softmax aggregation, one wave/node ----------
template<int H, int C, bool ELU, typename TO>
__global__ __launch_bounds__(256) void csr_fused(
    const int* __restrict__ off, const int* __restrict__ eids,
    const int* __restrict__ ei, const ushort_t* __restrict__ xl,
    const ushort_t* __restrict__ xr, const float* __restrict__ att,
    const float* __restrict__ bias, TO* __restrict__ out) {
  constexpr int HC = H * C;
  constexpr int CPL = HC / 64;     // channels per lane
  constexpr int GROUP = C / CPL;   // lanes per head
  const int n = (blockIdx.x * blockDim.x + threadIdx.x) >> 6;
  const int lane = threadIdx.x & 63;
  if (n >= NNODES) return;
  const int s0 = off[n], s1 = off[n + 1];

  float xrr[CPL], atr[CPL];
  if constexpr (CPL == 8) {
    unpack8(*(const int4*)(xr + (size_t)n * HC + lane * 8), xrr);
    const float4 a0 = *(const float4*)(att + lane * 8);
    const float4 a1 = *(const float4*)(att + lane * 8 + 4);
    atr[0] = a0.x; atr[1] = a0.y; atr[2] = a0.z; atr[3] = a0.w;
    atr[4] = a1.x; atr[5] = a1.y; atr[6] = a1.z; atr[7] = a1.w;
  } else {
    xrr[0] = b2f(xr[(size_t)n * HC + lane]);
    atr[0] = att[lane];
  }

  float m = -1e30f, s = 0.f;
  float acc[CPL] = {};

  // 2-deep prefetch of the gathered xl row
  int4 vnext = make_int4(0, 0, 0, 0);
  ushort_t unext = 0;
  if (s0 < s1) {
    const int srcn = ei[eids[s0]];
    if constexpr (CPL == 8) vnext = *(const int4*)(xl + (size_t)srcn * HC + lane * 8);
    else                    unext = xl[(size_t)srcn * HC + lane];
  }
  for (int i = s0; i < s1; ++i) {
    int4 vcur = vnext; ushort_t ucur = unext;
    if (i + 1 < s1) {
      const int srcn = ei[eids[i + 1]];
      if constexpr (CPL == 8) vnext = *(const int4*)(xl + (size_t)srcn * HC + lane * 8);
      else                    unext = xl[(size_t)srcn * HC + lane];
    }
    float zl[CPL];
    if constexpr (CPL == 8) unpack8(vcur, zl);
    else zl[0] = b2f(ucur);
    float e = 0.f;
    #pragma unroll
    for (int c = 0; c < CPL; ++c) {
      float z = zl[c] + xrr[c];
      z = (z > 0.f) ? z : 0.2f * z;
      e += z * atr[c];
    }
    #pragma unroll
    for (int o = 1; o < GROUP; o <<= 1)
      e += __shfl_xor(e, o, 64);
    if (e > m) {
      const float scale = __expf(m - e);
      s *= scale;
      #pragma unroll
      for (int c = 0; c < CPL; ++c) acc[c] *= scale;
      m = e;
    }
    const float w = __expf(e - m);
    s += w;
    #pragma unroll
    for (int c = 0; c < CPL; ++c) acc[c] += w * zl[c];
  }
  const float inv = 1.f / (s + 1e-16f);
  TO* po = out + (size_t)n * HC + lane * CPL;
  #pragma unroll
  for (int c = 0; c < CPL; ++c) {
    float v = acc[c] * inv + bias[lane * CPL + c];
    if (ELU) v = v > 0.f ? v : (__expf(v) - 1.f);
    stf(&po[c], v);
  }
}

// ---------- emergency: report ws_size via absmax ----------
__global__ void report_ws(float* __restrict__ out, float v) { out[0] = v; }

// ---------- orchestration ----------
extern "C" void kernel_launch(void* const* d_in, const int* in_sizes, int n_in,
                              void* d_out, int out_size, void* d_ws, size_t ws_size,
                              hipStream_t stream) {
  const float* x  = (const float*)d_in[0];
  const int*   ei = (const int*)d_in[1];
  float* out = (float*)d_out;
  char* ws = (char*)d_ws;

  // layout (bytes), all 16B-aligned
  ushort_t* hbuf = (ushort_t*)(ws);                   // N*512 bf16  51,200,000
  ushort_t* xlb  = (ushort_t*)(ws + 51200000ull);     // N*512 bf16  51,200,000
  ushort_t* xrb  = (ushort_t*)(ws + 102400000ull);    // N*512 bf16  51,200,000
  ushort_t* xb   = (ushort_t*)(ws + 153600000ull);    // N*128 bf16  12,800,000
  ushort_t* WtLR = (ushort_t*)(ws + 166400000ull);    // 2*512*512*2 = 2,097,152
  int* bsum  = (int*)(ws + 168500000ull);
  int* bpref = (int*)(ws + 168501024ull);
  int* coff  = (int*)(ws + 168600000ull);             // N+1
  int* cpos  = (int*)(ws + 168800008ull);             // N
  int* cdeg  = (int*)(ws + 169000012ull);             // N
  int* eids  = (int*)(ws + 169200016ull);             // E -> end 170,000,016

  if (ws_size < 170000016ull) {
    report_ws<<<1, 1, 0, stream>>>(out, (float)ws_size);
    return;
  }

  // input cast + CSR build (once)
  cast_x<<<(NNODES * 128 / 8 + 255) / 256, 256, 0, stream>>>(x, xb, NNODES * 128 / 8);
  csr_zero<<<(NNODES + 255) / 256, 256, 0, stream>>>(cdeg);
  csr_hist<<<(NEDGES + 255) / 256, 256, 0, stream>>>(ei, cdeg);
  scan_k1<<<SCAN_BLK, SCAN_TPB, 0, stream>>>(cdeg, bsum);
  scan_k2<<<1, 64, 0, stream>>>(bsum, bpref, coff);
  scan_k3<<<SCAN_BLK, SCAN_TPB, 0, stream>>>(cdeg, bpref, coff, cpos);
  csr_fill<<<(NEDGES + 255) / 256, 256, 0, stream>>>(ei, cpos, eids);

  const int ngrid = (NNODES * 64 + 255) / 256;

  for (int layer = 0; layer < 4; ++layer) {
    const int base = 2 + layer * 6;
    const float* Wl  = (const float*)d_in[base + 0];
    const float* bl  = (const float*)d_in[base + 1];
    const float* Wr  = (const float*)d_in[base + 2];
    const float* br  = (const float*)d_in[base + 3];
    const float* att = (const float*)d_in[base + 4];
    const float* b   = (const float*)d_in[base + 5];

    const ushort_t* A = (layer == 0) ? xb : hbuf;
    const int K  = (layer == 0) ? 128 : 512;
    const int Mo = (layer == 3) ? 64 : 512;

    wt_prep2<<<(2 * K * Mo + 255) / 256, 256, 0, stream>>>(Wl, Wr, WtLR, K, Mo);

    dim3 gg(2 * Mo / 128, (NNODES + 127) / 128);   // col-fastest -> A panel reuse
    gemm2_mfma<<<gg, 256, 0, stream>>>(A, WtLR, bl, br, xlb, xrb, NNODES, K, Mo);

    if (layer < 3) {
      csr_fused<4, 128, true, ushort_t><<<ngrid, 256, 0, stream>>>(
          coff, eids, ei, xlb, xrb, att, b, hbuf);
    } else {
      csr_fused<1, 64, false, float><<<ngrid, 256, 0, stream>>>(
          coff, eids, ei, xlb, xrb, att, b, out);
    }
  }
}

// Round 8
// 528.930 us; speedup vs baseline: 21.7909x; 1.2023x over previous
//
#include <hip/hip_runtime.h>
#include <math.h>

#define NNODES 50000
#define NEDGES 200000

typedef unsigned short ushort_t;
using frag8 = __attribute__((ext_vector_type(8))) short;   // 8 x bf16
using facc4 = __attribute__((ext_vector_type(4))) float;   // 4 x f32

// ---------- bf16 helpers (bit-level, RNE) ----------
static __device__ __forceinline__ ushort_t f2b(float f) {
  union { float f; unsigned u; } v; v.f = f;
  unsigned r = v.u + 0x7FFFu + ((v.u >> 16) & 1u);
  return (ushort_t)(r >> 16);
}
static __device__ __forceinline__ float b2f(unsigned hi) {
  return __uint_as_float(hi << 16);
}
static __device__ __forceinline__ void unpack8(const int4 v, float* f) {
  f[0] = b2f((unsigned)v.x & 0xFFFFu); f[1] = b2f((unsigned)v.x >> 16);
  f[2] = b2f((unsigned)v.y & 0xFFFFu); f[3] = b2f((unsigned)v.y >> 16);
  f[4] = b2f((unsigned)v.z & 0xFFFFu); f[5] = b2f((unsigned)v.z >> 16);
  f[6] = b2f((unsigned)v.w & 0xFFFFu); f[7] = b2f((unsigned)v.w >> 16);
}
static __device__ __forceinline__ void stf(float* p, float v) { *p = v; }
static __device__ __forceinline__ void stf(ushort_t* p, float v) { *p = f2b(v); }

// ---------- cast x (fp32) -> bf16, 8 elems/thread ----------
__global__ void cast_x(const float* __restrict__ x, ushort_t* __restrict__ xb, int total8) {
  int t = blockIdx.x * 256 + threadIdx.x;
  if (t >= total8) return;
  const float4* p = (const float4*)(x + (size_t)t * 8);
  float4 a = p[0], b = p[1];
  int4 w = make_int4(
      (int)((unsigned)f2b(a.x) | ((unsigned)f2b(a.y) << 16)),
      (int)((unsigned)f2b(a.z) | ((unsigned)f2b(a.w) << 16)),
      (int)((unsigned)f2b(b.x) | ((unsigned)f2b(b.y) << 16)),
      (int)((unsigned)f2b(b.z) | ((unsigned)f2b(b.w) << 16)));
  *(int4*)(xb + (size_t)t * 8) = w;
}

// ---------- weight transpose + cast (L and R into one buffer) ----------
__global__ void wt_prep2(const float* __restrict__ Wl, const float* __restrict__ Wr,
                         ushort_t* __restrict__ WtLR, int K, int Mo) {
  int t = blockIdx.x * 256 + threadIdx.x;
  const int tot = K * Mo;
  if (t >= 2 * tot) return;
  const float* W = (t < tot) ? Wl : Wr;
  int u = (t < tot) ? t : t - tot;
  int c = u / K, k = u - c * K;
  WtLR[t] = f2b(W[(size_t)k * Mo + c]);
}

// ---------- fused MFMA GEMM: [xl|xr][N,Mo](bf16) = A[N,K](bf16) * WtLR + bias ----------
// 1D grid, XCD-bijective swizzle (m204); orig order = row-panel-major, col-fastest.
__global__ __launch_bounds__(256) void gemm2_mfma(
    const ushort_t* __restrict__ A, const ushort_t* __restrict__ WtLR,
    const float* __restrict__ bl, const float* __restrict__ br,
    ushort_t* __restrict__ xlb, ushort_t* __restrict__ xrb,
    int N, int K, int Mo, int ncb) {
  __shared__ __align__(16) char smem[34816];   // union: Al+Bl (16KB) / Cl (34KB)
  auto Al = reinterpret_cast<ushort_t(*)[128][8]>(smem);          // [4][128][8]
  auto Bl = reinterpret_cast<ushort_t(*)[128][8]>(smem + 8192);   // [4][128][8]
  auto Cl = reinterpret_cast<ushort_t(*)[136]>(smem);             // [128][136]

  // bijective XCD-chunked swizzle: each XCD gets contiguous orig range
  const int nwg = gridDim.x;
  const int q = nwg >> 3, r = nwg & 7;
  const int xcd = blockIdx.x & 7, pos = blockIdx.x >> 3;
  const int orig = (xcd < r ? xcd * (q + 1) : r * (q + 1) + (xcd - r) * q) + pos;
  const int rp = orig / ncb, cb = orig - rp * ncb;
  const int brow = rp * 128;
  const int bcol = cb * 128;                 // within [0, 2*Mo)

  const int tid = threadIdx.x;
  const int wave = tid >> 6, lane = tid & 63;
  const int wr = wave >> 1, wc = wave & 1;   // 2x2 waves
  const int l15 = lane & 15, l4 = lane >> 4;

  facc4 acc[4][4] = {};

  const int srow = tid >> 1;         // 0..127
  const int skb  = (tid & 1) * 2;    // kblock 0 or 2
  for (int k0 = 0; k0 < K; k0 += 32) {
    {
      const int grow = brow + srow;
      int4 a0, a1;
      if (grow < N) {
        const int4* pa = (const int4*)(A + (size_t)grow * K + k0 + skb * 8);
        a0 = pa[0]; a1 = pa[1];
      } else {
        a0 = a1 = make_int4(0, 0, 0, 0);
      }
      *(int4*)&Al[skb + 0][srow][0] = a0;
      *(int4*)&Al[skb + 1][srow][0] = a1;
      const int4* pb = (const int4*)(WtLR + (size_t)(bcol + srow) * K + k0 + skb * 8);
      int4 b0 = pb[0], b1 = pb[1];
      *(int4*)&Bl[skb + 0][srow][0] = b0;
      *(int4*)&Bl[skb + 1][srow][0] = b1;
    }
    __syncthreads();
    frag8 af[4], bfg[4];
    #pragma unroll
    for (int i = 0; i < 4; ++i)
      af[i] = *(const frag8*)&Al[l4][wr * 64 + i * 16 + l15][0];
    #pragma unroll
    for (int j = 0; j < 4; ++j)
      bfg[j] = *(const frag8*)&Bl[l4][wc * 64 + j * 16 + l15][0];
    #pragma unroll
    for (int i = 0; i < 4; ++i)
      #pragma unroll
      for (int j = 0; j < 4; ++j)
        acc[i][j] = __builtin_amdgcn_mfma_f32_16x16x32_bf16(af[i], bfg[j], acc[i][j], 0, 0, 0);
    __syncthreads();
  }

  // ---- epilogue: stage bf16 C tile in LDS, then coalesced int4 writeout ----
  #pragma unroll
  for (int j = 0; j < 4; ++j) {
    const int lcol = wc * 64 + j * 16 + l15;
    const int col2 = bcol + lcol;
    const float bv = (col2 < Mo) ? bl[col2] : br[col2 - Mo];
    #pragma unroll
    for (int i = 0; i < 4; ++i) {
      const int lrow = wr * 64 + i * 16 + l4 * 4;
      #pragma unroll
      for (int rr = 0; rr < 4; ++rr)
        Cl[lrow + rr][lcol] = f2b(acc[i][j][rr] + bv);
    }
  }
  __syncthreads();
  {
    const int row = tid >> 1;          // 0..127
    const int half = tid & 1;          // 64-col halves
    const int grow = brow + row;
    if (grow < N) {
      const int colb = half * 64;
      const int col2 = bcol + colb;    // 64-aligned; side uniform across 64 cols
      const bool isL = col2 < Mo;
      ushort_t* dst = (isL ? xlb : xrb) + (size_t)grow * Mo + (isL ? col2 : col2 - Mo);
      #pragma unroll
      for (int k = 0; k < 8; ++k) {
        int4 v = *(const int4*)&Cl[row][colb + k * 8];
        *(int4*)(dst + k * 8) = v;
      }
    }
  }
}

// ---------- CSR build (by dst) ----------
__global__ void csr_zero(int* __restrict__ deg) {
  int t = blockIdx.x * blockDim.x + threadIdx.x;
  if (t < NNODES) deg[t] = 0;
}
__global__ void csr_hist(const int* __restrict__ ei, int* __restrict__ deg) {
  int e = blockIdx.x * blockDim.x + threadIdx.x;
  if (e >= NEDGES) return;
  atomicAdd(&deg[ei[NEDGES + e]], 1);
}

#define SCAN_TPB 256
#define SCAN_EPT 4
#define SCAN_CHUNK (SCAN_TPB * SCAN_EPT)                       // 1024
#define SCAN_BLK ((NNODES + SCAN_CHUNK - 1) / SCAN_CHUNK)      // 49

__global__ __launch_bounds__(SCAN_TPB) void scan_k1(const int* __restrict__ deg,
                                                    int* __restrict__ bsum) {
  __shared__ int sd[SCAN_TPB];
  const int tid = threadIdx.x;
  const int tbase = blockIdx.x * SCAN_CHUNK + tid * SCAN_EPT;
  int s = 0;
  #pragma unroll
  for (int j = 0; j < SCAN_EPT; ++j) {
    int idx = tbase + j;
    if (idx < NNODES) s += deg[idx];
  }
  sd[tid] = s;
  __syncthreads();
  for (int d = SCAN_TPB / 2; d > 0; d >>= 1) {
    if (tid < d) sd[tid] += sd[tid + d];
    __syncthreads();
  }
  if (tid == 0) bsum[blockIdx.x] = sd[0];
}

__global__ __launch_bounds__(64) void scan_k2(const int* __restrict__ bsum,
                                              int* __restrict__ bpref,
                                              int* __restrict__ off) {
  __shared__ int sd[64];
  const int tid = threadIdx.x;
  sd[tid] = (tid < SCAN_BLK) ? bsum[tid] : 0;
  __syncthreads();
  for (int d = 1; d < 64; d <<= 1) {
    int t = (tid >= d) ? sd[tid - d] : 0;
    __syncthreads();
    sd[tid] += t;
    __syncthreads();
  }
  if (tid < SCAN_BLK) bpref[tid] = (tid == 0) ? 0 : sd[tid - 1];
  if (tid == 0) off[NNODES] = NEDGES;
}

__global__ __launch_bounds__(SCAN_TPB) void scan_k3(const int* __restrict__ deg,
                                                    const int* __restrict__ bpref,
                                                    int* __restrict__ off,
                                                    int* __restrict__ pos) {
  __shared__ int sd[SCAN_TPB];
  const int tid = threadIdx.x;
  const int tbase = blockIdx.x * SCAN_CHUNK + tid * SCAN_EPT;
  int v[SCAN_EPT];
  int s = 0;
  #pragma unroll
  for (int j = 0; j < SCAN_EPT; ++j) {
    int idx = tbase + j;
    v[j] = (idx < NNODES) ? deg[idx] : 0;
    s += v[j];
  }
  sd[tid] = s;
  __syncthreads();
  for (int d = 1; d < SCAN_TPB; d <<= 1) {
    int t = (tid >= d) ? sd[tid - d] : 0;
    __syncthreads();
    sd[tid] += t;
    __syncthreads();
  }
  int run = bpref[blockIdx.x] + ((tid == 0) ? 0 : sd[tid - 1]);
  #pragma unroll
  for (int j = 0; j < SCAN_EPT; ++j) {
    int idx = tbase + j;
    if (idx < NNODES) { off[idx] = run; pos[idx] = run; run += v[j]; }
  }
}

__global__ void csr_fill(const int* __restrict__ ei, int* __restrict__ pos,
                         int* __restrict__ eids) {
  int e = blockIdx.x * blockDim.x + threadIdx.x;
  if (e >= NEDGES) return;
  int p = atomicAdd(&pos[ei[NEDGES + e]], 1);
  eids[p] = e;
}

// ---------- fused attention + online-softmax aggregation, one wave/node ----------
template<int H, int C, bool ELU, typename TO>
__global__ __launch_bounds__(256) void csr_fused(
    const int* __restrict__ off, const int* __restrict__ eids,
    const int* __restrict__ ei, const ushort_t* __restrict__ xl,
    const ushort_t* __restrict__ xr, const float* __restrict__ att,
    const float* __restrict__ bias, TO* __restrict__ out) {
  constexpr int HC = H * C;
  constexpr int CPL = HC / 64;
  constexpr int GROUP = C / CPL;
  const int n = (blockIdx.x * blockDim.x + threadIdx.x) >> 6;
  const int lane = threadIdx.x & 63;
  if (n >= NNODES) return;
  const int s0 = off[n], s1 = off[n + 1];

  float xrr[CPL], atr[CPL];
  if constexpr (CPL == 8) {
    unpack8(*(const int4*)(xr + (size_t)n * HC + lane * 8), xrr);
    const float4 a0 = *(const float4*)(att + lane * 8);
    const float4 a1 = *(const float4*)(att + lane * 8 + 4);
    atr[0] = a0.x; atr[1] = a0.y; atr[2] = a0.z; atr[3] = a0.w;
    atr[4] = a1.x; atr[5] = a1.y; atr[6] = a1.z; atr[7] = a1.w;
  } else {
    xrr[0] = b2f(xr[(size_t)n * HC + lane]);
    atr[0] = att[lane];
  }

  float m = -1e30f, s = 0.f;
  float acc[CPL] = {};

  int4 vnext = make_int4(0, 0, 0, 0);
  ushort_t unext = 0;
  if (s0 < s1) {
    const int srcn = ei[eids[s0]];
    if constexpr (CPL == 8) vnext = *(const int4*)(xl + (size_t)srcn * HC + lane * 8);
    else                    unext = xl[(size_t)srcn * HC + lane];
  }
  for (int i = s0; i < s1; ++i) {
    int4 vcur = vnext; ushort_t ucur = unext;
    if (i + 1 < s1) {
      const int srcn = ei[eids[i + 1]];
      if constexpr (CPL == 8) vnext = *(const int4*)(xl + (size_t)srcn * HC + lane * 8);
      else                    unext = xl[(size_t)srcn * HC + lane];
    }
    float zl[CPL];
    if constexpr (CPL == 8) unpack8(vcur, zl);
    else zl[0] = b2f(ucur);
    float e = 0.f;
    #pragma unroll
    for (int c = 0; c < CPL; ++c) {
      float z = zl[c] + xrr[c];
      z = (z > 0.f) ? z : 0.2f * z;
      e += z * atr[c];
    }
    #pragma unroll
    for (int o = 1; o < GROUP; o <<= 1)
      e += __shfl_xor(e, o, 64);
    if (e > m) {
      const float scale = __expf(m - e);
      s *= scale;
      #pragma unroll
      for (int c = 0; c < CPL; ++c) acc[c] *= scale;
      m = e;
    }
    const float w = __expf(e - m);
    s += w;
    #pragma unroll
    for (int c = 0; c < CPL; ++c) acc[c] += w * zl[c];
  }
  const float inv = 1.f / (s + 1e-16f);
  TO* po = out + (size_t)n * HC + lane * CPL;
  #pragma unroll
  for (int c = 0; c < CPL; ++c) {
    float v = acc[c] * inv + bias[lane * CPL + c];
    if (ELU) v = v > 0.f ? v : (__expf(v) - 1.f);
    stf(&po[c], v);
  }
}

// ---------- emergency: report ws_size via absmax ----------
__global__ void report_ws(float* __restrict__ out, float v) { out[0] = v; }

// ---------- orchestration ----------
extern "C" void kernel_launch(void* const* d_in, const int* in_sizes, int n_in,
                              void* d_out, int out_size, void* d_ws, size_t ws_size,
                              hipStream_t stream) {
  const float* x  = (const float*)d_in[0];
  const int*   ei = (const int*)d_in[1];
  float* out = (float*)d_out;
  char* ws = (char*)d_ws;

  // layout (bytes), all 16B-aligned
  ushort_t* hbuf = (ushort_t*)(ws);                   // N*512 bf16  51,200,000
  ushort_t* xlb  = (ushort_t*)(ws + 51200000ull);     // N*512 bf16  51,200,000
  ushort_t* xrb  = (ushort_t*)(ws + 102400000ull);    // N*512 bf16  51,200,000
  ushort_t* xb   = (ushort_t*)(ws + 153600000ull);    // N*128 bf16  12,800,000
  ushort_t* WtLR = (ushort_t*)(ws + 166400000ull);    // 2*512*512*2 = 2,097,152
  int* bsum  = (int*)(ws + 168500000ull);
  int* bpref = (int*)(ws + 168501024ull);
  int* coff  = (int*)(ws + 168600000ull);             // N+1
  int* cpos  = (int*)(ws + 168800008ull);             // N
  int* cdeg  = (int*)(ws + 169000012ull);             // N
  int* eids  = (int*)(ws + 169200016ull);             // E -> end 170,000,016

  if (ws_size < 170000016ull) {
    report_ws<<<1, 1, 0, stream>>>(out, (float)ws_size);
    return;
  }

  cast_x<<<(NNODES * 128 / 8 + 255) / 256, 256, 0, stream>>>(x, xb, NNODES * 128 / 8);
  csr_zero<<<(NNODES + 255) / 256, 256, 0, stream>>>(cdeg);
  csr_hist<<<(NEDGES + 255) / 256, 256, 0, stream>>>(ei, cdeg);
  scan_k1<<<SCAN_BLK, SCAN_TPB, 0, stream>>>(cdeg, bsum);
  scan_k2<<<1, 64, 0, stream>>>(bsum, bpref, coff);
  scan_k3<<<SCAN_BLK, SCAN_TPB, 0, stream>>>(cdeg, bpref, coff, cpos);
  csr_fill<<<(NEDGES + 255) / 256, 256, 0, stream>>>(ei, cpos, eids);

  const int ngrid = (NNODES * 64 + 255) / 256;
  const int nrp = (NNODES + 127) / 128;               // 391 row panels

  for (int layer = 0; layer < 4; ++layer) {
    const int base = 2 + layer * 6;
    const float* Wl  = (const float*)d_in[base + 0];
    const float* bl  = (const float*)d_in[base + 1];
    const float* Wr  = (const float*)d_in[base + 2];
    const float* br  = (const float*)d_in[base + 3];
    const float* att = (const float*)d_in[base + 4];
    const float* b   = (const float*)d_in[base + 5];

    const ushort_t* A = (layer == 0) ? xb : hbuf;
    const int K  = (layer == 0) ? 128 : 512;
    const int Mo = (layer == 3) ? 64 : 512;
    const int ncb = 2 * Mo / 128;                     // col blocks

    wt_prep2<<<(2 * K * Mo + 255) / 256, 256, 0, stream>>>(Wl, Wr, WtLR, K, Mo);

    gemm2_mfma<<<ncb * nrp, 256, 0, stream>>>(A, WtLR, bl, br, xlb, xrb,
                                              NNODES, K, Mo, ncb);

    if (layer < 3) {
      csr_fused<4, 128, true, ushort_t><<<ngrid, 256, 0, stream>>>(
          coff, eids, ei, xlb, xrb, att, b, hbuf);
    } else {
      csr_fused<1, 64, false, float><<<ngrid, 256, 0, stream>>>(
          coff, eids, ei, xlb, xrb, att, b, out);
    }
  }
}